// Round 12
// baseline (492.639 us; speedup 1.0000x reference)
//
#include <hip/hip_runtime.h>
#include <stdint.h>

typedef unsigned short ushort_t;

// Problem constants
#define NVOX   221184      // 2*48*48*48 voxels
#define NSTATE 7077888     // NVOX * 32 channels
// ws layout: stateA bf16 | stateB bf16 | wb f32 (biases) | wh u16 (frag tables) | flag
#define WB_CB   0          // conv_b[16]
#define WB_F0B  16         // fc0_b[128]
#define WB_TOT  160
// wh offsets (u16 units): pre-swizzled hi/lo bf16 fragment tables (R8/R9-verified)
#define CWH 0              // conv W frags [14 kst][64 lane][8]
#define CWL 7168
#define B0H 14336          // fc0 W frags [2 kst][8 nt][64][8]
#define B0L 22528
#define B1H 30720          // fc1 W frags [4 kt][2 ct][64][8]
#define B1L 34816
#define WH_TOT 38912       // u16

// LDS (u16 units) — 38 KB total (+1 KB maskb) -> 4 blocks/CU
#define XC0   0            // halo xc: 600 rows x 24 (16 ch + pad8; 48B rows, b128-aligned)
#define CVS0  14400        // cv scratch: 4 waves x 16 x 24
#define HS0   15936        // h scratch: 4 waves x (2 halves x 16 x 24) = 768 u16/wave
#define SH_TOT 19008       // u16 = 38016 B

typedef __attribute__((ext_vector_type(8))) short    s8v;    // 8 bf16 (4 VGPRs)
typedef __attribute__((ext_vector_type(4))) float    f32x4;  // MFMA C/D
typedef __attribute__((ext_vector_type(4))) ushort_t u16x4;  // 8B chunk
union AF { s8v v; u16x4 h[2]; ushort_t u[8]; };
#define MFMA(a,b,c) __builtin_amdgcn_mfma_f32_16x16x32_bf16((a),(b),(c),0,0,0)
// compiler-only memory barrier: same-wave DS ops are HW-in-order (R9-R11-verified pattern)
#define CBAR() __asm__ volatile("" ::: "memory")

// ---------- bf16 helpers ----------
__host__ __device__ __forceinline__ float bf2f(ushort_t u) {
  union { uint32_t u; float f; } v; v.u = ((uint32_t)u) << 16; return v.f;
}
__device__ __forceinline__ ushort_t f2bf(float f) {  // RNE, finite values
  union { float f; uint32_t u; } v; v.f = f;
  uint32_t r = (v.u + 0x7FFFu + ((v.u >> 16) & 1u)) >> 16;
  return (ushort_t)r;
}
__device__ __forceinline__ float ldin(const void* p, int i, uint32_t bf) {
  return bf ? bf2f(((const ushort_t*)p)[i]) : ((const float*)p)[i];
}

// ---------- JAX Threefry-2x32 (verified bit-exact R3) ----------
__host__ __device__ __forceinline__ void tf2x32(uint32_t k0, uint32_t k1,
                                                uint32_t x0, uint32_t x1,
                                                uint32_t& o0, uint32_t& o1) {
  uint32_t ks2 = k0 ^ k1 ^ 0x1BD11BDAu;
#define TFR(r) { x0 += x1; x1 = (x1 << r) | (x1 >> (32 - r)); x1 ^= x0; }
  x0 += k0; x1 += k1;
  TFR(13) TFR(15) TFR(26) TFR(6)
  x0 += k1;  x1 += ks2 + 1u;
  TFR(17) TFR(29) TFR(16) TFR(24)
  x0 += ks2; x1 += k0 + 2u;
  TFR(13) TFR(15) TFR(26) TFR(6)
  x0 += k0;  x1 += k1 + 3u;
  TFR(17) TFR(29) TFR(16) TFR(24)
  x0 += k1;  x1 += ks2 + 4u;
  TFR(13) TFR(15) TFR(26) TFR(6)
  x0 += ks2; x1 += k0 + 5u;
#undef TFR
  o0 = x0; o1 = x1;
}
__device__ __forceinline__ float mask_val(uint32_t k0, uint32_t k1, uint32_t vi) {
  uint32_t r0, r1;
  tf2x32(k0, k1, 0u, vi, r0, r1);
  uint32_t bits = r0 ^ r1;
  return ((bits >> 9) > 0x400000u) ? 1.0f : 0.0f;
}

// ---------- dtype detector (verified R3: flags f32) ----------
__global__ void nca_detect(const uint32_t* __restrict__ x, uint32_t* __restrict__ flag) {
  __shared__ int cnt[256];
  uint32_t w = x[threadIdx.x];
  uint32_t e = (w >> 7) & 0xFFu;
  cnt[threadIdx.x] = (e >= 110u && e <= 140u) ? 1 : 0;
  __syncthreads();
  for (int s = 128; s > 0; s >>= 1) {
    if ((int)threadIdx.x < s) cnt[threadIdx.x] += cnt[threadIdx.x + s];
    __syncthreads();
  }
  if (threadIdx.x == 0) *flag = (cnt[0] >= 160) ? 1u : 0u;
}

// ---------- weight prep (VERBATIM from R8/R9 — verified) ----------
__global__ __launch_bounds__(256) void nca_prep(
    const void* __restrict__ cw, const void* __restrict__ cb,
    const void* __restrict__ f0w, const void* __restrict__ f0b,
    const void* __restrict__ f1w, float* __restrict__ wb,
    ushort_t* __restrict__ wh, const uint32_t* __restrict__ flagp) {
  uint32_t bf = *flagp;
  int e = blockIdx.x * 256 + threadIdx.x;
  if (e < 16) { wb[WB_CB + e] = ldin(cb, e, bf); return; }
  if (e < 144) { wb[WB_F0B + (e - 16)] = ldin(f0b, e - 16, bf); return; }
  int eh = e - 144;
  if (eh >= 19456) return;
  float v; int hidx, lidx;
  if (eh < 7168) {
    int kst = eh >> 9; int l = (eh >> 3) & 63; int j = eh & 7;
    int qq = l >> 4; int o = l & 15;
    int t = kst * 2 + (qq >> 1); int i = (qq & 1) * 8 + j;
    v = (t <= 26) ? ldin(cw, o * 432 + i * 27 + t, bf) : 0.0f;
    hidx = CWH + eh; lidx = CWL + eh;
  } else if (eh < 15360) {
    int r = eh - 7168;
    int kst = r >> 12; int rem = r & 4095;
    int nt = rem >> 9; int l = (rem >> 3) & 63; int j = rem & 7;
    int qq = l >> 4; int n = nt * 16 + (l & 15);
    int k = kst * 32 + qq * 8 + j;
    v = (k < 48) ? ldin(f0w, n * 48 + k, bf) : 0.0f;
    hidx = B0H + r; lidx = B0L + r;
  } else {
    int r = eh - 15360;
    int kt = r >> 10; int rem = r & 1023;
    int n2 = rem >> 9; int l = (rem >> 3) & 63; int j = rem & 7;
    int qq = l >> 4; int c = n2 * 16 + (l & 15);
    int k = kt * 32 + qq * 8 + j;
    v = ldin(f1w, c * 128 + k, bf);
    hidx = B1H + r; lidx = B1L + r;
  }
  ushort_t hi = f2bf(v);
  float hf = bf2f(hi);
  ushort_t lo = f2bf(v - hf);
  wh[hidx] = hi; wh[lidx] = lo;
}

// ---------- init: bf16 state; ch0..15 = x, ch16..31 = 0 ----------
__global__ __launch_bounds__(256) void nca_init(const void* __restrict__ x,
                                                ushort_t* __restrict__ st,
                                                const uint32_t* __restrict__ flagp) {
  uint32_t bf = *flagp;
  int gid = blockIdx.x * 256 + threadIdx.x;
  ushort_t* po = st + (size_t)gid * 32;
  if (bf) {
    const ushort_t* xs = (const ushort_t*)x + (size_t)gid * 16;
    *(uint4*)(po)     = *(const uint4*)(xs);
    *(uint4*)(po + 8) = *(const uint4*)(xs + 8);
  } else {
    const float* xs = (const float*)x + (size_t)gid * 16;
#pragma unroll
    for (int c = 0; c < 16; c += 4) {
      float4 v = *(const float4*)(xs + c);
      u16x4 t;
      t[0] = f2bf(v.x); t[1] = f2bf(v.y); t[2] = f2bf(v.z); t[3] = f2bf(v.w);
      *(u16x4*)(po + c) = t;
    }
  }
  uint4 z = make_uint4(0, 0, 0, 0);
  *(uint4*)(po + 16) = z;
  *(uint4*)(po + 24) = z;
}

// ---------- one NCA step, MFMA v5: bf16 state + full-grid residency ----------
// v4 (R11, 393 us) + __launch_bounds__(256,4): measured VGPR=80 fits the
// 128-VGPR/16-wave cap with zero spill risk (R5 trap needs cap < live set);
// LDS 39 KB x 4 = 156 KB <= 160 KB. 4 blocks/CU x 256 CU = 1024 >= 864-block
// grid -> whole grid co-resident (kills the 768+96 two-round tail) and +33%
// waves to hide fc-phase LDS round-trip latency.
__global__ __launch_bounds__(256, 4) void nca_step(
    const ushort_t* __restrict__ sin, ushort_t* __restrict__ sout,
    const float* __restrict__ wb, const ushort_t* __restrict__ wh,
    uint32_t k0, uint32_t k1, void* __restrict__ outp,
    const uint32_t* __restrict__ flagp, int fin) {
  __shared__ ushort_t SH[SH_TOT];
  __shared__ float maskb[256];
  uint32_t bf = *flagp;

  int bx = blockIdx.x;
  int tx = bx % 6;  int r0i = bx / 6;
  int ty = r0i % 6; int r1i = r0i / 6;
  int tz = r1i % 12; int b = r1i / 12;
  int tid = threadIdx.x;

  // ---- Phase A: halo xc -> LDS (b128 copies, no conversion); masks ----
  for (int hr = tid; hr < 600; hr += 256) {
    int hz = hr / 100, rm = hr % 100, hy = rm / 10, hx = rm % 10;
    int gd = tz * 4 + hz - 1; gd = (gd < 0) ? 1 : ((gd > 47) ? 46 : gd);
    int gh = ty * 8 + hy - 1; gh = (gh < 0) ? 1 : ((gh > 47) ? 46 : gh);
    int gw = tx * 8 + hx - 1; gw = (gw < 0) ? 1 : ((gw > 47) ? 46 : gw);
    const ushort_t* p = sin + ((((size_t)b * 48 + gd) * 48 + gh) * 48 + gw) * 32;
    ushort_t* dst = SH + XC0 + hr * 24;
    *(uint4*)(dst)     = *(const uint4*)(p);       // ch 0-7
    *(uint4*)(dst + 8) = *(const uint4*)(p + 8);   // ch 8-15
  }
  {
    int v = tid; int x = v & 7, y = (v >> 3) & 7, z = v >> 6;
    int gid = ((b * 48 + tz * 4 + z) * 48 + ty * 8 + y) * 48 + tx * 8 + x;
    maskb[v] = mask_val(k0, k1, (uint32_t)gid);
  }
  __syncthreads();   // the ONLY block barrier

  int lane = tid & 63, wave = tid >> 6;
  int q = lane >> 4, mcol = lane & 15;
  int ql = q & 1, qh = q >> 1;
  const int cvs = CVS0 + wave * 384;
  const int hs  = HS0 + wave * 768;     // two 384-u16 halves

  // lane's column-voxel geometry per m-tile
  int hb[4]; int gvx[4];
#pragma unroll
  for (int mm = 0; mm < 4; mm++) {
    int v = (wave * 4 + mm) * 16 + mcol;
    int x = v & 7, y = (v >> 3) & 7, z = v >> 6;
    hb[mm] = (z + 1) * 100 + (y + 1) * 10 + (x + 1);
    gvx[mm] = ((b * 48 + tz * 4 + z) * 48 + ty * 8 + y) * 48 + tx * 8 + x;
  }

  // ---- conv: cv^T[o][v], kst outer (weights once), mm inner; FULL UNROLL ----
  f32x4 acc[4];
#pragma unroll
  for (int mm = 0; mm < 4; mm++) acc[mm] = (f32x4){0.f, 0.f, 0.f, 0.f};
#pragma unroll
  for (int kst = 0; kst < 14; kst++) {
    int t = kst * 2 + qh; if (t > 26) t = 26;     // padded taps hit zero weights
    int kz = t % 3, kxx = t / 9, kyy = (t / 3) % 3;
    int roff = (kz - 1) * 100 + (kxx - 1) * 10 + (kyy - 1);
    s8v bh = *(const s8v*)(wh + CWH + (size_t)(kst * 64 + lane) * 8);
    s8v bl = *(const s8v*)(wh + CWL + (size_t)(kst * 64 + lane) * 8);
#pragma unroll
    for (int mm = 0; mm < 4; mm++) {
      s8v a = *(const s8v*)(SH + (hb[mm] + roff) * 24 + ql * 8);
      acc[mm] = MFMA(bh, a, acc[mm]);
      acc[mm] = MFMA(bl, a, acc[mm]);
    }
  }

  // ---- din B-frags: k0 = [xc(0..15) | cv(16..31)], k1 = [xm(32..47) | 0] ----
  float4 cb4 = *(const float4*)(wb + WB_CB + q * 4);
  AF fk0[4], fk1[4];
#pragma unroll
  for (int mm = 0; mm < 4; mm++) {
    u16x4 pk;
    pk[0] = f2bf(acc[mm][0] + cb4.x);
    pk[1] = f2bf(acc[mm][1] + cb4.y);
    pk[2] = f2bf(acc[mm][2] + cb4.z);
    pk[3] = f2bf(acc[mm][3] + cb4.w);
    *(u16x4*)(SH + cvs + mcol * 24 + q * 4) = pk;   // cv^T -> [voxel][o] rows
    CBAR();
    int off0 = (q < 2) ? (hb[mm] * 24 + q * 8)                 // xc: center-tap halo row
                       : (cvs + mcol * 24 + (q - 2) * 8);      // cv
    fk0[mm].v = *(const s8v*)(SH + off0);
    CBAR();                                          // keep next mm's write after read
    if (q < 2) {
      // xm ch 16+q*8 .. 16+q*8+7, bf16 direct (16B, aligned)
      fk1[mm].v = *(const s8v*)(sin + (size_t)gvx[mm] * 32 + 16 + q * 8);
    } else {
#pragma unroll
      for (int j = 0; j < 8; j++) fk1[mm].u[j] = 0;
    }
  }

  // ---- fc0 (h^T) + fc1 (dx^T): kt outer (weights hoisted), mm inner ----
  f32x4 dxa[4][2];
#pragma unroll
  for (int mm = 0; mm < 4; mm++) {
    dxa[mm][0] = (f32x4){0.f, 0.f, 0.f, 0.f};
    dxa[mm][1] = (f32x4){0.f, 0.f, 0.f, 0.f};
  }
#pragma unroll
  for (int kt = 0; kt < 4; kt++) {
    int nt0 = kt * 2, nt1 = kt * 2 + 1;
    s8v w1h0 = *(const s8v*)(wh + B1H + (size_t)((nt0) * 64 + lane) * 8);
    s8v w1l0 = *(const s8v*)(wh + B1L + (size_t)((nt0) * 64 + lane) * 8);
    s8v w1h1 = *(const s8v*)(wh + B1H + (size_t)((nt1) * 64 + lane) * 8);
    s8v w1l1 = *(const s8v*)(wh + B1L + (size_t)((nt1) * 64 + lane) * 8);
    s8v f0h00 = *(const s8v*)(wh + B0H + (size_t)((nt0) * 64 + lane) * 8);     // t2=0,kst0
    s8v f0l00 = *(const s8v*)(wh + B0L + (size_t)((nt0) * 64 + lane) * 8);
    s8v f0h01 = *(const s8v*)(wh + B0H + (size_t)((8 + nt0) * 64 + lane) * 8); // t2=0,kst1
    s8v f0l01 = *(const s8v*)(wh + B0L + (size_t)((8 + nt0) * 64 + lane) * 8);
    s8v f0h10 = *(const s8v*)(wh + B0H + (size_t)((nt1) * 64 + lane) * 8);     // t2=1,kst0
    s8v f0l10 = *(const s8v*)(wh + B0L + (size_t)((nt1) * 64 + lane) * 8);
    s8v f0h11 = *(const s8v*)(wh + B0H + (size_t)((8 + nt1) * 64 + lane) * 8); // t2=1,kst1
    s8v f0l11 = *(const s8v*)(wh + B0L + (size_t)((8 + nt1) * 64 + lane) * 8);
    float4 b40 = *(const float4*)(wb + WB_F0B + nt0 * 16 + q * 4);
    float4 b41 = *(const float4*)(wb + WB_F0B + nt1 * 16 + q * 4);
#pragma unroll
    for (int mm = 0; mm < 4; mm++) {
      f32x4 a0 = (f32x4){b40.x, b40.y, b40.z, b40.w};
      a0 = MFMA(f0h00, fk0[mm].v, a0);
      a0 = MFMA(f0l00, fk0[mm].v, a0);
      a0 = MFMA(f0h01, fk1[mm].v, a0);
      a0 = MFMA(f0l01, fk1[mm].v, a0);
      f32x4 a1 = (f32x4){b41.x, b41.y, b41.z, b41.w};
      a1 = MFMA(f0h10, fk0[mm].v, a1);
      a1 = MFMA(f0l10, fk0[mm].v, a1);
      a1 = MFMA(f0h11, fk1[mm].v, a1);
      a1 = MFMA(f0l11, fk1[mm].v, a1);
      u16x4 p0, p1;
      p0[0] = f2bf(fmaxf(a0[0], 0.f)); p0[1] = f2bf(fmaxf(a0[1], 0.f));
      p0[2] = f2bf(fmaxf(a0[2], 0.f)); p0[3] = f2bf(fmaxf(a0[3], 0.f));
      p1[0] = f2bf(fmaxf(a1[0], 0.f)); p1[1] = f2bf(fmaxf(a1[1], 0.f));
      p1[2] = f2bf(fmaxf(a1[2], 0.f)); p1[3] = f2bf(fmaxf(a1[3], 0.f));
      *(u16x4*)(SH + hs + mcol * 24 + q * 4) = p0;          // half0 (t2=0)
      *(u16x4*)(SH + hs + 384 + mcol * 24 + q * 4) = p1;    // half1 (t2=1)
      CBAR();
      // a2 frag: k = kt*32 + q*8 + j -> entirely in half (q>>1), n' = (q&1)*8 + j
      s8v a2 = *(const s8v*)(SH + hs + (q >> 1) * 384 + mcol * 24 + (q & 1) * 8);
      CBAR();                                               // order next mm's writes
      dxa[mm][0] = MFMA(w1h0, a2, dxa[mm][0]);
      dxa[mm][0] = MFMA(w1l0, a2, dxa[mm][0]);
      dxa[mm][1] = MFMA(w1h1, a2, dxa[mm][1]);
      dxa[mm][1] = MFMA(w1l1, a2, dxa[mm][1]);
    }
  }

  // ---- epilogue: residual + mask; ch0 frozen; bf16 state (or d_out if final) ----
#pragma unroll
  for (int mm = 0; mm < 4; mm++) {
    float mk = maskb[wave * 64 + mm * 16 + mcol];
#pragma unroll
    for (int ct = 0; ct < 2; ct++) {
      u16x4 od;
      if (ct == 0) od = *(const u16x4*)(SH + hb[mm] * 24 + q * 4);          // xc from LDS halo
      else         od = *(const u16x4*)(sin + (size_t)gvx[mm] * 32 + 16 + q * 4); // xm
      float o0 = bf2f(od[0]), o1 = bf2f(od[1]), o2 = bf2f(od[2]), o3 = bf2f(od[3]);
      float n0 = fmaf(dxa[mm][ct][0], mk, o0);
      float n1 = fmaf(dxa[mm][ct][1], mk, o1);
      float n2 = fmaf(dxa[mm][ct][2], mk, o2);
      float n3 = fmaf(dxa[mm][ct][3], mk, o3);
      if (ct == 0 && q == 0) n0 = o0;   // c==0 frozen (bit-exact copy)
      size_t off = (size_t)gvx[mm] * 32 + ct * 16 + q * 4;
      if (fin) {
        if (bf) {
          u16x4 w;
          w[0] = f2bf(n0); w[1] = f2bf(n1); w[2] = f2bf(n2); w[3] = f2bf(n3);
          *(u16x4*)((ushort_t*)outp + off) = w;
        } else {
          *(float4*)((float*)outp + off) = make_float4(n0, n1, n2, n3);
        }
      } else {
        u16x4 w;
        w[0] = f2bf(n0); w[1] = f2bf(n1); w[2] = f2bf(n2); w[3] = f2bf(n3);
        *(u16x4*)(sout + off) = w;
      }
    }
  }
}

extern "C" void kernel_launch(void* const* d_in, const int* in_sizes, int n_in,
                              void* d_out, int out_size, void* d_ws, size_t ws_size,
                              hipStream_t stream) {
  ushort_t* base = (ushort_t*)d_ws;
  ushort_t* sA = base;                       // bf16 state A
  ushort_t* sB = base + NSTATE;              // bf16 state B
  float* wb = (float*)(base + 2 * (size_t)NSTATE);
  ushort_t* wh = (ushort_t*)(wb + WB_TOT);
  uint32_t* flag = (uint32_t*)(wh + WH_TOT);

  nca_detect<<<1, 256, 0, stream>>>((const uint32_t*)d_in[0], flag);
  nca_prep<<<77, 256, 0, stream>>>(d_in[1], d_in[2], d_in[3], d_in[4], d_in[5],
                                   wb, wh, flag);
  nca_init<<<NVOX / 256, 256, 0, stream>>>(d_in[0], sA, flag);

  ushort_t* src = sA;
  ushort_t* dst = sB;
  for (int s = 0; s < 10; s++) {
    uint32_t o0, o1;
    tf2x32(0u, 42u, 0u, (uint32_t)s, o0, o1);   // folded step key, host-side
    nca_step<<<864, 256, 0, stream>>>(src, dst, wb, wh, o0, o1,
                                      d_out, flag, (s == 9) ? 1 : 0);
    ushort_t* tmp = src; src = dst; dst = tmp;
  }
}

// Round 13
// 367.120 us; speedup vs baseline: 1.3419x; 1.3419x over previous
//
#include <hip/hip_runtime.h>
#include <stdint.h>

typedef unsigned short ushort_t;

// Problem constants
#define NVOX   221184      // 2*48*48*48 voxels
#define NHALF  3538944     // NVOX * 16 (one 16-ch bf16 plane)
// ws layout (u16): sA_xc | sA_xm | sB_xc | sB_xm | wb f32 | wh u16 | flag
#define WB_CB   0          // conv_b[16]
#define WB_F0B  16         // fc0_b[128]
#define WB_TOT  160
// wh offsets (u16 units): pre-swizzled hi/lo bf16 fragment tables (R8/R9-verified)
#define CWH 0              // conv W frags [14 kst][64 lane][8]
#define CWL 7168
#define B0H 14336          // fc0 W frags [2 kst][8 nt][64][8]
#define B0L 22528
#define B1H 30720          // fc1 W frags [4 kt][2 ct][64][8]
#define B1L 34816
#define WH_TOT 38912       // u16

// LDS (u16 units) — 38 KB total (+1 KB maskb) -> 4 blocks/CU (LDS-limited)
#define XC0   0            // halo xc: 600 rows x 24 (16 ch + pad8; 48B rows, b128-aligned)
#define CVS0  14400        // cv scratch: 4 waves x 16 x 24
#define HS0   15936        // h scratch: 4 waves x (2 halves x 16 x 24) = 768 u16/wave
#define SH_TOT 19008       // u16 = 38016 B

typedef __attribute__((ext_vector_type(8))) short    s8v;    // 8 bf16 (4 VGPRs)
typedef __attribute__((ext_vector_type(4))) float    f32x4;  // MFMA C/D
typedef __attribute__((ext_vector_type(4))) ushort_t u16x4;  // 8B chunk
union AF { s8v v; u16x4 h[2]; ushort_t u[8]; };
#define MFMA(a,b,c) __builtin_amdgcn_mfma_f32_16x16x32_bf16((a),(b),(c),0,0,0)
// compiler-only memory barrier: same-wave DS ops are HW-in-order (R9-R12-verified pattern)
#define CBAR() __asm__ volatile("" ::: "memory")

// ---------- bf16 helpers ----------
__host__ __device__ __forceinline__ float bf2f(ushort_t u) {
  union { uint32_t u; float f; } v; v.u = ((uint32_t)u) << 16; return v.f;
}
__device__ __forceinline__ ushort_t f2bf(float f) {  // RNE, finite values
  union { float f; uint32_t u; } v; v.f = f;
  uint32_t r = (v.u + 0x7FFFu + ((v.u >> 16) & 1u)) >> 16;
  return (ushort_t)r;
}
__device__ __forceinline__ float ldin(const void* p, int i, uint32_t bf) {
  return bf ? bf2f(((const ushort_t*)p)[i]) : ((const float*)p)[i];
}

// ---------- JAX Threefry-2x32 (verified bit-exact R3) ----------
__host__ __device__ __forceinline__ void tf2x32(uint32_t k0, uint32_t k1,
                                                uint32_t x0, uint32_t x1,
                                                uint32_t& o0, uint32_t& o1) {
  uint32_t ks2 = k0 ^ k1 ^ 0x1BD11BDAu;
#define TFR(r) { x0 += x1; x1 = (x1 << r) | (x1 >> (32 - r)); x1 ^= x0; }
  x0 += k0; x1 += k1;
  TFR(13) TFR(15) TFR(26) TFR(6)
  x0 += k1;  x1 += ks2 + 1u;
  TFR(17) TFR(29) TFR(16) TFR(24)
  x0 += ks2; x1 += k0 + 2u;
  TFR(13) TFR(15) TFR(26) TFR(6)
  x0 += k0;  x1 += k1 + 3u;
  TFR(17) TFR(29) TFR(16) TFR(24)
  x0 += k1;  x1 += ks2 + 4u;
  TFR(13) TFR(15) TFR(26) TFR(6)
  x0 += ks2; x1 += k0 + 5u;
#undef TFR
  o0 = x0; o1 = x1;
}
__device__ __forceinline__ float mask_val(uint32_t k0, uint32_t k1, uint32_t vi) {
  uint32_t r0, r1;
  tf2x32(k0, k1, 0u, vi, r0, r1);
  uint32_t bits = r0 ^ r1;
  return ((bits >> 9) > 0x400000u) ? 1.0f : 0.0f;
}

// ---------- dtype detector (verified R3: flags f32) ----------
__global__ void nca_detect(const uint32_t* __restrict__ x, uint32_t* __restrict__ flag) {
  __shared__ int cnt[256];
  uint32_t w = x[threadIdx.x];
  uint32_t e = (w >> 7) & 0xFFu;
  cnt[threadIdx.x] = (e >= 110u && e <= 140u) ? 1 : 0;
  __syncthreads();
  for (int s = 128; s > 0; s >>= 1) {
    if ((int)threadIdx.x < s) cnt[threadIdx.x] += cnt[threadIdx.x + s];
    __syncthreads();
  }
  if (threadIdx.x == 0) *flag = (cnt[0] >= 160) ? 1u : 0u;
}

// ---------- weight prep (VERBATIM from R8/R9 — verified) ----------
__global__ __launch_bounds__(256) void nca_prep(
    const void* __restrict__ cw, const void* __restrict__ cb,
    const void* __restrict__ f0w, const void* __restrict__ f0b,
    const void* __restrict__ f1w, float* __restrict__ wb,
    ushort_t* __restrict__ wh, const uint32_t* __restrict__ flagp) {
  uint32_t bf = *flagp;
  int e = blockIdx.x * 256 + threadIdx.x;
  if (e < 16) { wb[WB_CB + e] = ldin(cb, e, bf); return; }
  if (e < 144) { wb[WB_F0B + (e - 16)] = ldin(f0b, e - 16, bf); return; }
  int eh = e - 144;
  if (eh >= 19456) return;
  float v; int hidx, lidx;
  if (eh < 7168) {
    int kst = eh >> 9; int l = (eh >> 3) & 63; int j = eh & 7;
    int qq = l >> 4; int o = l & 15;
    int t = kst * 2 + (qq >> 1); int i = (qq & 1) * 8 + j;
    v = (t <= 26) ? ldin(cw, o * 432 + i * 27 + t, bf) : 0.0f;
    hidx = CWH + eh; lidx = CWL + eh;
  } else if (eh < 15360) {
    int r = eh - 7168;
    int kst = r >> 12; int rem = r & 4095;
    int nt = rem >> 9; int l = (rem >> 3) & 63; int j = rem & 7;
    int qq = l >> 4; int n = nt * 16 + (l & 15);
    int k = kst * 32 + qq * 8 + j;
    v = (k < 48) ? ldin(f0w, n * 48 + k, bf) : 0.0f;
    hidx = B0H + r; lidx = B0L + r;
  } else {
    int r = eh - 15360;
    int kt = r >> 10; int rem = r & 1023;
    int n2 = rem >> 9; int l = (rem >> 3) & 63; int j = rem & 7;
    int qq = l >> 4; int c = n2 * 16 + (l & 15);
    int k = kt * 32 + qq * 8 + j;
    v = ldin(f1w, c * 128 + k, bf);
    hidx = B1H + r; lidx = B1L + r;
  }
  ushort_t hi = f2bf(v);
  float hf = bf2f(hi);
  ushort_t lo = f2bf(v - hf);
  wh[hidx] = hi; wh[lidx] = lo;
}

// ---------- init: split bf16 state; xc = x, xm = 0 ----------
__global__ __launch_bounds__(256) void nca_init(const void* __restrict__ x,
                                                ushort_t* __restrict__ sxc,
                                                ushort_t* __restrict__ sxm,
                                                const uint32_t* __restrict__ flagp) {
  uint32_t bf = *flagp;
  int gid = blockIdx.x * 256 + threadIdx.x;
  ushort_t* pc = sxc + (size_t)gid * 16;
  if (bf) {
    const ushort_t* xs = (const ushort_t*)x + (size_t)gid * 16;
    *(uint4*)(pc)     = *(const uint4*)(xs);
    *(uint4*)(pc + 8) = *(const uint4*)(xs + 8);
  } else {
    const float* xs = (const float*)x + (size_t)gid * 16;
#pragma unroll
    for (int c = 0; c < 16; c += 4) {
      float4 v = *(const float4*)(xs + c);
      u16x4 t;
      t[0] = f2bf(v.x); t[1] = f2bf(v.y); t[2] = f2bf(v.z); t[3] = f2bf(v.w);
      *(u16x4*)(pc + c) = t;
    }
  }
  uint4 z = make_uint4(0, 0, 0, 0);
  ushort_t* pm = sxm + (size_t)gid * 16;
  *(uint4*)(pm)     = z;
  *(uint4*)(pm + 8) = z;
}

// ---------- one NCA step, MFMA v6: split xc/xm state planes ----------
// v4 structure (R11-verified, 393 us) at (256,3) [R12 lesson: (256,4) shaves
// VGPR 80->64 and spills; residency was already 4 blocks/CU via LDS], plus:
// state split into xc[NVOX*16] / xm[NVOX*16] planes so halo reads are
// sector-dense (32B contiguous x 10 voxels) and epilogue stores cover
// contiguous 512B spans completely (R12: WRITE 66 MB vs 14 MB payload from
// partial-sector 8B stores into 64B interleaved records).
__global__ __launch_bounds__(256, 3) void nca_step(
    const ushort_t* __restrict__ sxc, const ushort_t* __restrict__ sxm,
    ushort_t* __restrict__ dxc, ushort_t* __restrict__ dxm,
    const float* __restrict__ wb, const ushort_t* __restrict__ wh,
    uint32_t k0, uint32_t k1, void* __restrict__ outp,
    const uint32_t* __restrict__ flagp, int fin) {
  __shared__ ushort_t SH[SH_TOT];
  __shared__ float maskb[256];
  uint32_t bf = *flagp;

  int bx = blockIdx.x;
  int tx = bx % 6;  int r0i = bx / 6;
  int ty = r0i % 6; int r1i = r0i / 6;
  int tz = r1i % 12; int b = r1i / 12;
  int tid = threadIdx.x;

  // ---- Phase A: halo xc -> LDS (b128 copies, sector-dense); masks ----
  for (int hr = tid; hr < 600; hr += 256) {
    int hz = hr / 100, rm = hr % 100, hy = rm / 10, hx = rm % 10;
    int gd = tz * 4 + hz - 1; gd = (gd < 0) ? 1 : ((gd > 47) ? 46 : gd);
    int gh = ty * 8 + hy - 1; gh = (gh < 0) ? 1 : ((gh > 47) ? 46 : gh);
    int gw = tx * 8 + hx - 1; gw = (gw < 0) ? 1 : ((gw > 47) ? 46 : gw);
    const ushort_t* p = sxc + ((((size_t)b * 48 + gd) * 48 + gh) * 48 + gw) * 16;
    ushort_t* dst = SH + XC0 + hr * 24;
    *(uint4*)(dst)     = *(const uint4*)(p);       // ch 0-7
    *(uint4*)(dst + 8) = *(const uint4*)(p + 8);   // ch 8-15
  }
  {
    int v = tid; int x = v & 7, y = (v >> 3) & 7, z = v >> 6;
    int gid = ((b * 48 + tz * 4 + z) * 48 + ty * 8 + y) * 48 + tx * 8 + x;
    maskb[v] = mask_val(k0, k1, (uint32_t)gid);
  }
  __syncthreads();   // the ONLY block barrier

  int lane = tid & 63, wave = tid >> 6;
  int q = lane >> 4, mcol = lane & 15;
  int ql = q & 1, qh = q >> 1;
  const int cvs = CVS0 + wave * 384;
  const int hs  = HS0 + wave * 768;     // two 384-u16 halves

  // lane's column-voxel geometry per m-tile
  int hb[4]; int gvx[4];
#pragma unroll
  for (int mm = 0; mm < 4; mm++) {
    int v = (wave * 4 + mm) * 16 + mcol;
    int x = v & 7, y = (v >> 3) & 7, z = v >> 6;
    hb[mm] = (z + 1) * 100 + (y + 1) * 10 + (x + 1);
    gvx[mm] = ((b * 48 + tz * 4 + z) * 48 + ty * 8 + y) * 48 + tx * 8 + x;
  }

  // ---- conv: cv^T[o][v], kst outer (weights once), mm inner; FULL UNROLL ----
  f32x4 acc[4];
#pragma unroll
  for (int mm = 0; mm < 4; mm++) acc[mm] = (f32x4){0.f, 0.f, 0.f, 0.f};
#pragma unroll
  for (int kst = 0; kst < 14; kst++) {
    int t = kst * 2 + qh; if (t > 26) t = 26;     // padded taps hit zero weights
    int kz = t % 3, kxx = t / 9, kyy = (t / 3) % 3;
    int roff = (kz - 1) * 100 + (kxx - 1) * 10 + (kyy - 1);
    s8v bh = *(const s8v*)(wh + CWH + (size_t)(kst * 64 + lane) * 8);
    s8v bl = *(const s8v*)(wh + CWL + (size_t)(kst * 64 + lane) * 8);
#pragma unroll
    for (int mm = 0; mm < 4; mm++) {
      s8v a = *(const s8v*)(SH + (hb[mm] + roff) * 24 + ql * 8);
      acc[mm] = MFMA(bh, a, acc[mm]);
      acc[mm] = MFMA(bl, a, acc[mm]);
    }
  }

  // ---- din B-frags: k0 = [xc(0..15) | cv(16..31)], k1 = [xm(32..47) | 0] ----
  float4 cb4 = *(const float4*)(wb + WB_CB + q * 4);
  AF fk0[4], fk1[4];
#pragma unroll
  for (int mm = 0; mm < 4; mm++) {
    u16x4 pk;
    pk[0] = f2bf(acc[mm][0] + cb4.x);
    pk[1] = f2bf(acc[mm][1] + cb4.y);
    pk[2] = f2bf(acc[mm][2] + cb4.z);
    pk[3] = f2bf(acc[mm][3] + cb4.w);
    *(u16x4*)(SH + cvs + mcol * 24 + q * 4) = pk;   // cv^T -> [voxel][o] rows
    CBAR();
    int off0 = (q < 2) ? (hb[mm] * 24 + q * 8)                 // xc: center-tap halo row
                       : (cvs + mcol * 24 + (q - 2) * 8);      // cv
    fk0[mm].v = *(const s8v*)(SH + off0);
    CBAR();                                          // keep next mm's write after read
    if (q < 2) {
      // xm ch q*8 .. q*8+7, bf16 direct (16B, aligned, coalesced)
      fk1[mm].v = *(const s8v*)(sxm + (size_t)gvx[mm] * 16 + q * 8);
    } else {
#pragma unroll
      for (int j = 0; j < 8; j++) fk1[mm].u[j] = 0;
    }
  }

  // ---- fc0 (h^T) + fc1 (dx^T): kt outer (weights hoisted), mm inner ----
  f32x4 dxa[4][2];
#pragma unroll
  for (int mm = 0; mm < 4; mm++) {
    dxa[mm][0] = (f32x4){0.f, 0.f, 0.f, 0.f};
    dxa[mm][1] = (f32x4){0.f, 0.f, 0.f, 0.f};
  }
#pragma unroll
  for (int kt = 0; kt < 4; kt++) {
    int nt0 = kt * 2, nt1 = kt * 2 + 1;
    s8v w1h0 = *(const s8v*)(wh + B1H + (size_t)((nt0) * 64 + lane) * 8);
    s8v w1l0 = *(const s8v*)(wh + B1L + (size_t)((nt0) * 64 + lane) * 8);
    s8v w1h1 = *(const s8v*)(wh + B1H + (size_t)((nt1) * 64 + lane) * 8);
    s8v w1l1 = *(const s8v*)(wh + B1L + (size_t)((nt1) * 64 + lane) * 8);
    s8v f0h00 = *(const s8v*)(wh + B0H + (size_t)((nt0) * 64 + lane) * 8);     // t2=0,kst0
    s8v f0l00 = *(const s8v*)(wh + B0L + (size_t)((nt0) * 64 + lane) * 8);
    s8v f0h01 = *(const s8v*)(wh + B0H + (size_t)((8 + nt0) * 64 + lane) * 8); // t2=0,kst1
    s8v f0l01 = *(const s8v*)(wh + B0L + (size_t)((8 + nt0) * 64 + lane) * 8);
    s8v f0h10 = *(const s8v*)(wh + B0H + (size_t)((nt1) * 64 + lane) * 8);     // t2=1,kst0
    s8v f0l10 = *(const s8v*)(wh + B0L + (size_t)((nt1) * 64 + lane) * 8);
    s8v f0h11 = *(const s8v*)(wh + B0H + (size_t)((8 + nt1) * 64 + lane) * 8); // t2=1,kst1
    s8v f0l11 = *(const s8v*)(wh + B0L + (size_t)((8 + nt1) * 64 + lane) * 8);
    float4 b40 = *(const float4*)(wb + WB_F0B + nt0 * 16 + q * 4);
    float4 b41 = *(const float4*)(wb + WB_F0B + nt1 * 16 + q * 4);
#pragma unroll
    for (int mm = 0; mm < 4; mm++) {
      f32x4 a0 = (f32x4){b40.x, b40.y, b40.z, b40.w};
      a0 = MFMA(f0h00, fk0[mm].v, a0);
      a0 = MFMA(f0l00, fk0[mm].v, a0);
      a0 = MFMA(f0h01, fk1[mm].v, a0);
      a0 = MFMA(f0l01, fk1[mm].v, a0);
      f32x4 a1 = (f32x4){b41.x, b41.y, b41.z, b41.w};
      a1 = MFMA(f0h10, fk0[mm].v, a1);
      a1 = MFMA(f0l10, fk0[mm].v, a1);
      a1 = MFMA(f0h11, fk1[mm].v, a1);
      a1 = MFMA(f0l11, fk1[mm].v, a1);
      u16x4 p0, p1;
      p0[0] = f2bf(fmaxf(a0[0], 0.f)); p0[1] = f2bf(fmaxf(a0[1], 0.f));
      p0[2] = f2bf(fmaxf(a0[2], 0.f)); p0[3] = f2bf(fmaxf(a0[3], 0.f));
      p1[0] = f2bf(fmaxf(a1[0], 0.f)); p1[1] = f2bf(fmaxf(a1[1], 0.f));
      p1[2] = f2bf(fmaxf(a1[2], 0.f)); p1[3] = f2bf(fmaxf(a1[3], 0.f));
      *(u16x4*)(SH + hs + mcol * 24 + q * 4) = p0;          // half0 (t2=0)
      *(u16x4*)(SH + hs + 384 + mcol * 24 + q * 4) = p1;    // half1 (t2=1)
      CBAR();
      // a2 frag: k = kt*32 + q*8 + j -> entirely in half (q>>1), n' = (q&1)*8 + j
      s8v a2 = *(const s8v*)(SH + hs + (q >> 1) * 384 + mcol * 24 + (q & 1) * 8);
      CBAR();                                               // order next mm's writes
      dxa[mm][0] = MFMA(w1h0, a2, dxa[mm][0]);
      dxa[mm][0] = MFMA(w1l0, a2, dxa[mm][0]);
      dxa[mm][1] = MFMA(w1h1, a2, dxa[mm][1]);
      dxa[mm][1] = MFMA(w1l1, a2, dxa[mm][1]);
    }
  }

  // ---- epilogue: residual + mask; ch0 frozen; split-plane stores ----
  // Per (mm,ct) the wave's 64 x 8B stores cover a CONTIGUOUS 512B span of
  // dxc/dxm (16 consecutive voxels x 32B) — full sector coverage.
#pragma unroll
  for (int mm = 0; mm < 4; mm++) {
    float mk = maskb[wave * 64 + mm * 16 + mcol];
#pragma unroll
    for (int ct = 0; ct < 2; ct++) {
      u16x4 od;
      if (ct == 0) od = *(const u16x4*)(SH + hb[mm] * 24 + q * 4);              // xc (LDS halo)
      else         od = *(const u16x4*)(sxm + (size_t)gvx[mm] * 16 + q * 4);    // xm
      float o0 = bf2f(od[0]), o1 = bf2f(od[1]), o2 = bf2f(od[2]), o3 = bf2f(od[3]);
      float n0 = fmaf(dxa[mm][ct][0], mk, o0);
      float n1 = fmaf(dxa[mm][ct][1], mk, o1);
      float n2 = fmaf(dxa[mm][ct][2], mk, o2);
      float n3 = fmaf(dxa[mm][ct][3], mk, o3);
      if (ct == 0 && q == 0) n0 = o0;   // c==0 frozen (bit-exact copy)
      if (fin) {
        size_t off = (size_t)gvx[mm] * 32 + ct * 16 + q * 4;   // interleaved output
        if (bf) {
          u16x4 w;
          w[0] = f2bf(n0); w[1] = f2bf(n1); w[2] = f2bf(n2); w[3] = f2bf(n3);
          *(u16x4*)((ushort_t*)outp + off) = w;
        } else {
          *(float4*)((float*)outp + off) = make_float4(n0, n1, n2, n3);
        }
      } else {
        u16x4 w;
        w[0] = f2bf(n0); w[1] = f2bf(n1); w[2] = f2bf(n2); w[3] = f2bf(n3);
        ushort_t* dp = (ct == 0) ? dxc : dxm;
        *(u16x4*)(dp + (size_t)gvx[mm] * 16 + q * 4) = w;
      }
    }
  }
}

extern "C" void kernel_launch(void* const* d_in, const int* in_sizes, int n_in,
                              void* d_out, int out_size, void* d_ws, size_t ws_size,
                              hipStream_t stream) {
  ushort_t* base = (ushort_t*)d_ws;
  ushort_t* sAxc = base;                     // bf16 xc plane A
  ushort_t* sAxm = base + NHALF;             // bf16 xm plane A
  ushort_t* sBxc = base + 2 * (size_t)NHALF; // bf16 xc plane B
  ushort_t* sBxm = base + 3 * (size_t)NHALF; // bf16 xm plane B
  float* wb = (float*)(base + 4 * (size_t)NHALF);
  ushort_t* wh = (ushort_t*)(wb + WB_TOT);
  uint32_t* flag = (uint32_t*)(wh + WH_TOT);

  nca_detect<<<1, 256, 0, stream>>>((const uint32_t*)d_in[0], flag);
  nca_prep<<<77, 256, 0, stream>>>(d_in[1], d_in[2], d_in[3], d_in[4], d_in[5],
                                   wb, wh, flag);
  nca_init<<<NVOX / 256, 256, 0, stream>>>(d_in[0], sAxc, sAxm, flag);

  ushort_t* sxc = sAxc; ushort_t* sxm = sAxm;
  ushort_t* dxc = sBxc; ushort_t* dxm = sBxm;
  for (int s = 0; s < 10; s++) {
    uint32_t o0, o1;
    tf2x32(0u, 42u, 0u, (uint32_t)s, o0, o1);   // folded step key, host-side
    nca_step<<<864, 256, 0, stream>>>(sxc, sxm, dxc, dxm, wb, wh, o0, o1,
                                      d_out, flag, (s == 9) ? 1 : 0);
    ushort_t* t0 = sxc; sxc = dxc; dxc = t0;
    ushort_t* t1 = sxm; sxm = dxm; dxm = t1;
  }
}